// Round 6
// baseline (3832.832 us; speedup 1.0000x reference)
//
#include <hip/hip_runtime.h>

// IntegratedNCA R6: MFMA 4-way split-bf16 (all dropped terms <= 2^-36), low-order
// groups accumulated FIRST from zero (reference-class rounding), (h,h) group last,
// bias in fp32 epilogue. fp32-VALU 128->16; exact-fp32 life gate.
// K layout: 10 groups x 48 cols = 480 cols = 15 K-steps of 32.
//   gidx: 0=(h,m) 1=(m,h) 2=(h,l) 3=(m,m) 4=(l,h) 5=(h,q) 6=(m,l) 7=(l,m) 8=(q,h) 9=(h,h)
//   a-type tab 0x39244, w-type tab 0x6C61 (2 bits/group).
// Panel row (pixel): [ah|am|al|aq] x48 bf16 = 384 B, 16B slots, XOR-swz slot^(row&7).

typedef short short8 __attribute__((ext_vector_type(8)));
typedef float floatx4 __attribute__((ext_vector_type(4)));

#define CCH   16
#define HID   128
#define BATCH 16
#define HH    128
#define WW    128
#define NIN   112
#define STEPS 10
#define NKS   15
#define ROWB  384
#define NPIX  128          // pixels per block (8x16 tile)
#define ATAB  0x39244
#define WTAB  0x6C61

__device__ inline unsigned short f2bf(float f) {          // RN-even fp32->bf16
    unsigned u = __float_as_uint(f);
    u += 0x7fffu + ((u >> 16) & 1u);
    return (unsigned short)(u >> 16);
}
__device__ inline float bf2f(unsigned short h) { return __uint_as_float(((unsigned)h) << 16); }

// ---------------- prep: folded bias, W2 transpose, 4-way W1 fragment pack ----------------
__global__ __launch_bounds__(256) void nca_prep(
    const float* __restrict__ W1, const float* __restrict__ b1,
    const float* __restrict__ w,  const float* __restrict__ W2,
    float* __restrict__ biasw, float* __restrict__ W2t, unsigned short* __restrict__ W1p)
{
    const int t = threadIdx.x;
    for (int i = t; i < BATCH * HID; i += 256) {
        int b = i / HID, h = i % HID;
        float acc = b1[h];
        const float* wrow  = w  + b * 64;
        const float* W1row = W1 + h * NIN + 48;
        #pragma unroll
        for (int j = 0; j < 64; ++j) acc = fmaf(W1row[j], wrow[j], acc);
        biasw[i] = acc;
    }
    for (int i = t; i < HID * CCH; i += 256) {
        int h = i / CCH, c = i % CCH;
        W2t[h * CCH + c] = W2[c * HID + h];
    }
    // W1p[ks][Mt][lane][j]: A-frag (m=lane&15, k=(lane>>4)*8+j), w-split type per group.
    for (int i = t; i < NKS * 8 * 64 * 8; i += 256) {
        int j = i & 7, lane = (i >> 3) & 63, Mt = (i >> 9) & 7, ks = i >> 12;
        int col = ks * 32 + ((lane >> 4) << 3) + j;         // 0..479
        int grp = col / 48, within = col - grp * 48;
        int u = (WTAB >> (grp << 1)) & 3;
        int h = Mt * 16 + (lane & 15);
        float base = W1[h * NIN + within];
        unsigned short wh = f2bf(base), v;
        if (u == 0) v = wh;
        else {
            float r1 = base - bf2f(wh);
            unsigned short wm = f2bf(r1);
            if (u == 1) v = wm;
            else {
                float r2 = r1 - bf2f(wm);
                unsigned short wl = f2bf(r2);
                v = (u == 2) ? wl : f2bf(r2 - bf2f(wl));
            }
        }
        W1p[i] = v;
    }
}

// ---------------- per-step kernel: 128 threads = 8x16 pixel tile ----------------
__global__ __launch_bounds__(128, 1) void nca_step(
    const float* __restrict__ xin, float* __restrict__ xout,
    const unsigned short* __restrict__ W1p, const float* __restrict__ W2t,
    const float* __restrict__ b2, const float* __restrict__ biasw)
{
    __shared__ __align__(16) unsigned char panel[NPIX * ROWB];   // 48 KB

    const int b   = blockIdx.z;
    const int ty0 = blockIdx.y * 8, tx0 = blockIdx.x * 16;
    const int tid  = threadIdx.x;            // 0..127 = pixel in tile
    const int lane = tid & 63, wv = tid >> 6;
    const int q = lane >> 4, pcol = lane & 15;
    const float* xb = xin + b * (CCH * HH * WW);

    // ---- taps from global (clamped addr + zero mask == zero-pad), sobel, 4-way split ----
    const int py = tid >> 4, px = tid & 15;
    const int gy = ty0 + py, gx = tx0 + px;
    int   o0,o1,o2,o3,o4,o5,o6,o7,o8;
    float m0,m1,m2,m3,m4,m5,m6,m7,m8;
    {
        int cym = max(gy - 1, 0), cyp = min(gy + 1, HH - 1);
        int cxm = max(gx - 1, 0), cxp = min(gx + 1, WW - 1);
        float vym = (gy - 1 >= 0) ? 1.f : 0.f, vyp = (gy + 1 < HH) ? 1.f : 0.f;
        float vxm = (gx - 1 >= 0) ? 1.f : 0.f, vxp = (gx + 1 < WW) ? 1.f : 0.f;
        o0 = cym * WW + cxm; m0 = vym * vxm;
        o1 = cym * WW + gx;  m1 = vym;
        o2 = cym * WW + cxp; m2 = vym * vxp;
        o3 = gy  * WW + cxm; m3 = vxm;
        o4 = gy  * WW + gx;  m4 = 1.f;
        o5 = gy  * WW + cxp; m5 = vxp;
        o6 = cyp * WW + cxm; m6 = vyp * vxm;
        o7 = cyp * WW + gx;  m7 = vyp;
        o8 = cyp * WW + cxp; m8 = vyp * vxp;
    }
    unsigned short hsv[48], msv[48], lsv[48], qsv[48];
    bool pre_life = false;
    #pragma unroll
    for (int c = 0; c < CCH; ++c) {
        const float* xc = xb + c * (HH * WW);
        float t0 = xc[o0]*m0, t1 = xc[o1]*m1, t2 = xc[o2]*m2;
        float t3 = xc[o3]*m3, t4 = xc[o4]*m4, t5 = xc[o5]*m5;
        float t6 = xc[o6]*m6, t7 = xc[o7]*m7, t8 = xc[o8]*m8;
        float sgx = (t2 - t0) + 2.f * (t5 - t3) + (t8 - t6);
        float sgy = (t6 - t0) + 2.f * (t7 - t1) + (t8 - t2);
        if (c == 3) {
            float mm = fmaxf(fmaxf(fmaxf(t0, t1), fmaxf(t2, t3)),
                             fmaxf(fmaxf(t4, t5), fmaxf(t6, fmaxf(t7, t8))));
            pre_life = (mm > 0.1f);
        }
        float vals[3] = {t4, sgx, sgy};
        #pragma unroll
        for (int s = 0; s < 3; ++s) {
            float v = vals[s];
            unsigned short h0 = f2bf(v);  float r1 = v  - bf2f(h0);
            unsigned short m1_ = f2bf(r1); float r2 = r1 - bf2f(m1_);
            unsigned short l1 = f2bf(r2);
            hsv[s*16 + c] = h0; msv[s*16 + c] = m1_;
            lsv[s*16 + c] = l1; qsv[s*16 + c] = f2bf(r2 - bf2f(l1));
        }
    }
    {
        unsigned char* rowp = panel + tid * ROWB;
        const int swz = (tid & 7) << 4;
        const unsigned short* secs[4] = {hsv, msv, lsv, qsv};
        #pragma unroll
        for (int sec = 0; sec < 4; ++sec) {
            const unsigned short* sv = secs[sec];
            #pragma unroll
            for (int s = 0; s < 6; ++s) {
                uint4 u;
                u.x = (unsigned)sv[s*8+0] | ((unsigned)sv[s*8+1] << 16);
                u.y = (unsigned)sv[s*8+2] | ((unsigned)sv[s*8+3] << 16);
                u.z = (unsigned)sv[s*8+4] | ((unsigned)sv[s*8+5] << 16);
                u.w = (unsigned)sv[s*8+6] | ((unsigned)sv[s*8+7] << 16);
                *(uint4*)(rowp + (((sec * 6 + s) * 16) ^ swz)) = u;
            }
        }
    }
    __syncthreads();

    // ---- GEMM1 (MFMA, 15 K-steps, zero-init; (h,h) group is cols 432..479 = last) ----
    floatx4 acc[8][4];
    #pragma unroll
    for (int Mt = 0; Mt < 8; ++Mt)
        #pragma unroll
        for (int n2 = 0; n2 < 4; ++n2)
            acc[Mt][n2] = (floatx4){0.f, 0.f, 0.f, 0.f};

    short8 afA[8], afB[8];
    #pragma unroll
    for (int Mt = 0; Mt < 8; ++Mt)
        afA[Mt] = *(const short8*)(W1p + ((0 * 8 + Mt) * 64 + lane) * 8);

    #pragma unroll
    for (int ks = 0; ks < NKS; ++ks) {
        if ((ks & 1) == 0) {
            if (ks < NKS - 1) {
                #pragma unroll
                for (int Mt = 0; Mt < 8; ++Mt)
                    afB[Mt] = *(const short8*)(W1p + (((ks + 1) * 8 + Mt) * 64 + lane) * 8);
            }
        } else {
            if (ks < NKS - 1) {
                #pragma unroll
                for (int Mt = 0; Mt < 8; ++Mt)
                    afA[Mt] = *(const short8*)(W1p + (((ks + 1) * 8 + Mt) * 64 + lane) * 8);
            }
        }
        int col0 = ks * 32 + (q << 3);
        int grp = (col0 * 171) >> 13;                 // col0/48, valid to 479
        int within = col0 - grp * 48;
        int vsel = (ATAB >> (grp << 1)) & 3;          // a-split type for this group
        int kb = vsel * 96 + (within << 1);
        short8 bfr[4];
        #pragma unroll
        for (int n2 = 0; n2 < 4; ++n2) {
            int prow = wv * 64 + n2 * 16 + pcol;
            bfr[n2] = *(const short8*)(panel + prow * ROWB + (kb ^ ((prow & 7) << 4)));
        }
        if ((ks & 1) == 0) {
            #pragma unroll
            for (int n2 = 0; n2 < 4; ++n2)
                #pragma unroll
                for (int Mt = 0; Mt < 8; ++Mt)
                    acc[Mt][n2] = __builtin_amdgcn_mfma_f32_16x16x32_bf16(afA[Mt], bfr[n2], acc[Mt][n2], 0, 0, 0);
        } else {
            #pragma unroll
            for (int n2 = 0; n2 < 4; ++n2)
                #pragma unroll
                for (int Mt = 0; Mt < 8; ++Mt)
                    acc[Mt][n2] = __builtin_amdgcn_mfma_f32_16x16x32_bf16(afB[Mt], bfr[n2], acc[Mt][n2], 0, 0, 0);
        }
    }

    // ---- GEMM2 (fp32 VALU), bias added here: lane owns h = Mt*16 + q*4 + r ----
    float dsp[4][16];
    #pragma unroll
    for (int n2 = 0; n2 < 4; ++n2)
        #pragma unroll
        for (int c = 0; c < 16; ++c) dsp[n2][c] = 0.f;
    #pragma unroll
    for (int Mt = 0; Mt < 8; ++Mt) {
        floatx4 bv = *(const floatx4*)(biasw + b * HID + Mt * 16 + q * 4);
        #pragma unroll
        for (int r = 0; r < 4; ++r) {
            const floatx4* w2p = (const floatx4*)(W2t + (Mt * 16 + q * 4 + r) * 16);
            floatx4 wa = w2p[0], wb = w2p[1], wc = w2p[2], wd = w2p[3];
            #pragma unroll
            for (int n2 = 0; n2 < 4; ++n2) {
                float hv = fmaxf(acc[Mt][n2][r] + bv[r], 0.f);
                dsp[n2][0]  = fmaf(hv, wa[0], dsp[n2][0]);
                dsp[n2][1]  = fmaf(hv, wa[1], dsp[n2][1]);
                dsp[n2][2]  = fmaf(hv, wa[2], dsp[n2][2]);
                dsp[n2][3]  = fmaf(hv, wa[3], dsp[n2][3]);
                dsp[n2][4]  = fmaf(hv, wb[0], dsp[n2][4]);
                dsp[n2][5]  = fmaf(hv, wb[1], dsp[n2][5]);
                dsp[n2][6]  = fmaf(hv, wb[2], dsp[n2][6]);
                dsp[n2][7]  = fmaf(hv, wb[3], dsp[n2][7]);
                dsp[n2][8]  = fmaf(hv, wc[0], dsp[n2][8]);
                dsp[n2][9]  = fmaf(hv, wc[1], dsp[n2][9]);
                dsp[n2][10] = fmaf(hv, wc[2], dsp[n2][10]);
                dsp[n2][11] = fmaf(hv, wc[3], dsp[n2][11]);
                dsp[n2][12] = fmaf(hv, wd[0], dsp[n2][12]);
                dsp[n2][13] = fmaf(hv, wd[1], dsp[n2][13]);
                dsp[n2][14] = fmaf(hv, wd[2], dsp[n2][14]);
                dsp[n2][15] = fmaf(hv, wd[3], dsp[n2][15]);
            }
        }
    }

    __syncthreads();                       // panel reads done -> reuse as ds buffer
    float* dsl = (float*)panel;            // [128][17] f32
    #pragma unroll
    for (int n2 = 0; n2 < 4; ++n2) {
        #pragma unroll
        for (int c = 0; c < 16; ++c) {
            float v = dsp[n2][c];
            v += __shfl_xor(v, 16);
            v += __shfl_xor(v, 32);
            if ((c >> 2) == q)
                dsl[(wv * 64 + n2 * 16 + pcol) * 17 + c] = v;
        }
    }
    __syncthreads();

    // ---- residual + life gate (owner thread = pixel tid), exact fp32 ----
    const int gidx = gy * WW + gx;
    float ds3 = dsl[tid * 17 + 3] + b2[3];
    float x3  = xb[3 * HH * WW + gidx];
    float alive = ((x3 + ds3) > 0.1f && pre_life) ? 1.f : 0.f;
    float* ob = xout + b * (CCH * HH * WW);
    #pragma unroll
    for (int c = 0; c < CCH; ++c) {
        float nv = xb[c * HH * WW + gidx] + dsl[tid * 17 + c] + b2[c];
        ob[c * HH * WW + gidx] = nv * alive;
    }
}

extern "C" void kernel_launch(void* const* d_in, const int* in_sizes, int n_in,
                              void* d_out, int out_size, void* d_ws, size_t ws_size,
                              hipStream_t stream) {
    const float* x   = (const float*)d_in[0];
    const float* w   = (const float*)d_in[1];
    const float* W1  = (const float*)d_in[2];
    const float* b1  = (const float*)d_in[3];
    const float* W2  = (const float*)d_in[4];
    const float* b2  = (const float*)d_in[5];
    float* out = (float*)d_out;

    float* ws0   = (float*)d_ws;                          // 16.8 MB ping-pong
    float* biasw = ws0 + BATCH * CCH * HH * WW;           // 2048 f32
    float* W2t   = biasw + BATCH * HID;                   // 2048 f32
    unsigned short* W1p = (unsigned short*)(W2t + HID * CCH); // 61440 u16

    nca_prep<<<1, 256, 0, stream>>>(W1, b1, w, W2, biasw, W2t, W1p);

    dim3 grid(WW / 16, HH / 8, BATCH);
    for (int s = 0; s < STEPS; ++s) {
        float* dst = (((STEPS - 1 - s) & 1) == 0) ? out : ws0;
        const float* src = (s == 0) ? x
                         : ((((STEPS - s) & 1) == 0) ? (const float*)out : (const float*)ws0);
        nca_step<<<grid, 128, 0, stream>>>(src, dst, W1p, W2t, b2, biasw);
    }
}